// Round 7
// baseline (181.173 us; speedup 1.0000x reference)
//
#include <hip/hip_runtime.h>

// Voxel pooling, fixed-capacity buckets.
// R7 = R5 with compile fix: __builtin_nontemporal_load needs native clang
// vector types, not HIP_vector_type structs -> ext_vector_type typedefs.
// Gather: lane=(group of 20)x(float4 of row) -> one 64-lane load covers 3
// bucket entries (6x fewer vmem instructions). pay/spill written nontemporal.

namespace {
constexpr int NVX = 128, NVY = 128, C = 80;
constexpr int B = 2, N = 6, D = 112, H = 16, W = 44;
constexpr int HW    = H * W;             // 704
constexpr int BN    = B * N;             // 12
constexpr int DHW   = D * HW;            // 78848
constexpr int NDHW  = N * DHW;           // 473088 (points per batch)
constexpr int TOTAL = B * NDHW;          // 946176
constexpr int NVOX  = B * NVY * NVX;     // 32768
constexpr int NROW  = BN * HW;           // 8448 ctx_t rows
constexpr int CAP   = 64;                // bucket capacity (lambda=28.9)
constexpr int SPILLCAP = 32768;

constexpr int HIST_BLOCKS = TOTAL / 4 / 256;            // 924 (exact)
constexpr int TR_BLOCKS   = BN * (C / 16) * (HW / 64);  // 660
constexpr int PRE_BLOCKS  = HIST_BLOCKS + TR_BLOCKS;    // 1584
}

typedef int   vint4   __attribute__((ext_vector_type(4)));
typedef float vfloat4 __attribute__((ext_vector_type(4)));

// ---- 1. fused: hist_fill (blocks < HIST_BLOCKS) | tiled transpose ----
__global__ __launch_bounds__(256) void pre_kernel(
    const int*   __restrict__ geom, const float* __restrict__ depth,
    const float* __restrict__ ctx,  float* __restrict__ ctx_t,
    int* __restrict__ counts, long long* __restrict__ pay,
    int* __restrict__ spillcnt, long long* __restrict__ spill)
{
    __shared__ float tile[16 * 68];
    if (blockIdx.x < HIST_BLOCKS) {
        const int t  = blockIdx.x * 256 + threadIdx.x;
        const int p0 = t * 4;
        const vint4* g4 = (const vint4*)(geom + (size_t)3 * p0);
        const vint4 ga = __builtin_nontemporal_load(g4 + 0);
        const vint4 gb = __builtin_nontemporal_load(g4 + 1);
        const vint4 gc = __builtin_nontemporal_load(g4 + 2);
        const vfloat4 dp = __builtin_nontemporal_load((const vfloat4*)(depth + p0));
        const int xs[4] = {ga.x, ga.w, gb.z, gc.y};
        const int ys[4] = {ga.y, gb.x, gb.w, gc.z};
        const float ds[4] = {dp.x, dp.y, dp.z, dp.w};
        #pragma unroll
        for (int u = 0; u < 4; ++u) {
            const int p = p0 + u;
            const int x = xs[u], y = ys[u];
            if ((unsigned)x >= (unsigned)NVX || (unsigned)y >= (unsigned)NVY) continue;
            const int b   = (p >= NDHW) ? 1 : 0;          // B == 2
            const int v   = (b * NVY + y) * NVX + x;
            const int bn  = (unsigned)p / (unsigned)DHW;
            const int hw  = (unsigned)p % (unsigned)HW;
            const int row = bn * HW + hw;
            const unsigned dep = (unsigned)__float_as_int(ds[u]);
            const int idx = atomicAdd(&counts[v], 1);
            if (idx < CAP) {
                const long long pv = ((long long)dep << 32) | (unsigned)row;
                __builtin_nontemporal_store(pv, &pay[(size_t)v * CAP + idx]);
            } else {
                int s = atomicAdd(spillcnt, 1);
                if (s < SPILLCAP) {
                    const long long pv =
                        ((long long)dep << 32) | (unsigned)(v * NROW + row);
                    __builtin_nontemporal_store(pv, &spill[s]);
                }
            }
        }
    } else {
        // transpose ctx (bn, c, hw) -> ctx_t (bn*HW + hw, c), 16c x 64hw tiles
        const int tb  = blockIdx.x - HIST_BLOCKS;
        const int bn  = tb / 55;
        const int rem = tb % 55;
        const int c0  = (rem / 11) * 16;
        const int hw0 = (rem % 11) * 64;
        const int t = threadIdx.x;
        const int cl = t >> 6, hwl = t & 63;
        #pragma unroll
        for (int r = 0; r < 4; ++r) {
            const int c = r * 4 + cl;
            tile[c * 68 + hwl] =
                ctx[(size_t)(bn * C + c0 + c) * HW + hw0 + hwl];
        }
        __syncthreads();
        const int cr = t & 15, hwr = t >> 4;
        #pragma unroll
        for (int r = 0; r < 4; ++r) {
            const int hw = r * 16 + hwr;
            ctx_t[(size_t)(bn * HW + hw0 + hw) * C + c0 + cr] =
                tile[cr * 68 + hw];
        }
    }
}

// ---- 2. gather: 1 wave/voxel; 3 entries per load instruction ----
__global__ __launch_bounds__(256) void gather_kernel(
    const int* __restrict__ counts, const long long* __restrict__ pay,
    const float* __restrict__ ctx_t, float* __restrict__ out)
{
    const int v    = blockIdx.x * 4 + (threadIdx.x >> 6);
    const int lane = threadIdx.x & 63;
    // group g in {0,1,2} of 20 lanes; lanes 60..63 inactive (g=3)
    const int g = (lane >= 40) ? ((lane >= 60) ? 3 : 2) : ((lane >= 20) ? 1 : 0);
    const int r = lane - g * 20;

    int cnt = counts[v];
    if (cnt > CAP) cnt = CAP;

    long long eb = __builtin_nontemporal_load(&pay[(size_t)v * CAP + lane]);
    int ex = (int)(unsigned)(eb & 0xffffffffu);              // row
    int ey = (int)(unsigned)((unsigned long long)eb >> 32);  // depth bits
    if (lane >= cnt) { ex = 0; ey = 0; }

    const vfloat4* __restrict__ ctx4 = (const vfloat4*)ctx_t;
    vfloat4 acc0 = {0.f, 0.f, 0.f, 0.f};
    vfloat4 acc1 = {0.f, 0.f, 0.f, 0.f};
    for (int j = 0; j < cnt; j += 6) {
        const int i0 = j + g, i1 = j + 3 + g;
        int   row0 = __shfl(ex, i0 & 63);
        float dep0 = __int_as_float(__shfl(ey, i0 & 63));
        int   row1 = __shfl(ex, i1 & 63);
        float dep1 = __int_as_float(__shfl(ey, i1 & 63));
        const bool a0 = (g < 3) && (i0 < cnt);
        const bool a1 = (g < 3) && (i1 < cnt);
        row0 = a0 ? row0 : 0;  dep0 = a0 ? dep0 : 0.f;
        row1 = a1 ? row1 : 0;  dep1 = a1 ? dep1 : 0.f;
        const vfloat4 c0 = ctx4[row0 * 20 + r];
        const vfloat4 c1 = ctx4[row1 * 20 + r];
        acc0 += dep0 * c0;
        acc1 += dep1 * c1;
    }
    vfloat4 acc = acc0 + acc1;
    // reduce groups 1,2 into group 0 (shfl reads pre-update values)
    acc.x += __shfl(acc.x, (lane + 20) & 63) + __shfl(acc.x, (lane + 40) & 63);
    acc.y += __shfl(acc.y, (lane + 20) & 63) + __shfl(acc.y, (lane + 40) & 63);
    acc.z += __shfl(acc.z, (lane + 20) & 63) + __shfl(acc.z, (lane + 40) & 63);
    acc.w += __shfl(acc.w, (lane + 20) & 63) + __shfl(acc.w, (lane + 40) & 63);

    if (lane < 20) ((vfloat4*)out)[(size_t)v * 20 + lane] = acc;
}

// ---- 3. spill fixup (statistically zero work) ----
__global__ __launch_bounds__(256) void spill_kernel(
    const int* __restrict__ spillcnt, const long long* __restrict__ spill,
    const float* __restrict__ ctx_t, float* __restrict__ out)
{
    const int nwaves = gridDim.x * 4;
    const int wave   = blockIdx.x * 4 + (threadIdx.x >> 6);
    const int lane   = threadIdx.x & 63;
    int cnt = *spillcnt;
    if (cnt > SPILLCAP) cnt = SPILLCAP;
    for (int i = wave; i < cnt; i += nwaves) {
        const long long e = spill[i];
        const int key = (int)(unsigned)(e & 0xffffffffu);
        const float dep = __int_as_float((int)(unsigned)((unsigned long long)e >> 32));
        const int v   = (unsigned)key / (unsigned)NROW;
        const int row = key - v * NROW;
        const float* c = ctx_t + (size_t)row * C;
        float* o = out + (size_t)v * C;
        unsafeAtomicAdd(o + lane, dep * c[lane]);
        if (lane < C - 64) unsafeAtomicAdd(o + 64 + lane, dep * c[64 + lane]);
    }
}

extern "C" void kernel_launch(void* const* d_in, const int* in_sizes, int n_in,
                              void* d_out, int out_size, void* d_ws, size_t ws_size,
                              hipStream_t stream) {
    const int*   geom  = (const int*)d_in[0];
    const float* depth = (const float*)d_in[1];
    const float* ctx   = (const float*)d_in[2];
    float*       out   = (float*)d_out;

    char* ws = (char*)d_ws;
    int*       counts   = (int*)ws;       ws += ((size_t)(NVOX + 64) * 4 + 255) / 256 * 256;
    int*       spillcnt = counts + NVOX;                 // zeroed with counts
    long long* pay      = (long long*)ws; ws += ((size_t)NVOX * CAP * 8 + 255) / 256 * 256;
    long long* spill    = (long long*)ws; ws += ((size_t)SPILLCAP * 8 + 255) / 256 * 256;
    float*     ctx_t    = (float*)ws;

    (void)hipMemsetAsync(counts, 0, (size_t)(NVOX + 64) * 4, stream);

    pre_kernel   <<<dim3(PRE_BLOCKS), dim3(256), 0, stream>>>(
                    geom, depth, ctx, ctx_t, counts, pay, spillcnt, spill);
    gather_kernel<<<dim3(NVOX / 4), dim3(256), 0, stream>>>(counts, pay, ctx_t, out);
    spill_kernel <<<dim3(64), dim3(256), 0, stream>>>(spillcnt, spill, ctx_t, out);
}